// Round 12
// baseline (306.052 us; speedup 1.0000x reference)
//
#include <hip/hip_runtime.h>
#include <hip/hip_fp16.h>

// Problem constants (match reference file)
#define NN 100000
#define NE 1600000
#define NG 64

// dst-bucketing for the CSR build
#define BSHIFT 7
#define BUCKW (1 << BSHIFT)                 // 128 nodes per bucket
#define NBUCK ((NN + BUCKW - 1) >> BSHIFT)  // 782
#define BIN_CHUNK 8192

// ---- fp16 8-wide helpers (activations stored fp16, math in fp32) ----
union H8 { float4 f4; __half2 h2[4]; };
__device__ __forceinline__ void h8_to_f(const H8& h, float* f) {
    float2 a = __half22float2(h.h2[0]);
    float2 b = __half22float2(h.h2[1]);
    float2 c = __half22float2(h.h2[2]);
    float2 d = __half22float2(h.h2[3]);
    f[0]=a.x; f[1]=a.y; f[2]=b.x; f[3]=b.y; f[4]=c.x; f[5]=c.y; f[6]=d.x; f[7]=d.y;
}
__device__ __forceinline__ H8 f_to_h8(const float* f) {
    H8 h;
    h.h2[0] = __floats2half2_rn(f[0], f[1]);
    h.h2[1] = __floats2half2_rn(f[2], f[3]);
    h.h2[2] = __floats2half2_rn(f[4], f[5]);
    h.h2[3] = __floats2half2_rn(f[6], f[7]);
    return h;
}

// ---------------- bucket histogram (LDS-aggregated) ----------------
__global__ __launch_bounds__(256) void bucket_hist_kernel(const int* __restrict__ dst,
                                                          int* __restrict__ bucket_cnt, int E) {
    __shared__ int h[NBUCK];
    for (int i = threadIdx.x; i < NBUCK; i += 256) h[i] = 0;
    __syncthreads();
    int stride = gridDim.x * 256;
    for (int e = blockIdx.x * 256 + threadIdx.x; e < E; e += stride)
        atomicAdd(&h[dst[e] >> BSHIFT], 1);
    __syncthreads();
    for (int i = threadIdx.x; i < NBUCK; i += 256)
        if (h[i]) atomicAdd(&bucket_cnt[i], h[i]);
}

// ---------------- bucket scan: single block ----------------
__global__ void bucket_scan_kernel(const int* __restrict__ bcnt, int* __restrict__ boff,
                                   int* __restrict__ bcur) {
    __shared__ int buf[2][1024];
    int t = threadIdx.x;
    int v = (t < NBUCK) ? bcnt[t] : 0;
    buf[0][t] = v;
    __syncthreads();
    int cur = 0;
    for (int off = 1; off < 1024; off <<= 1) {
        int x = buf[cur][t];
        if (t >= off) x += buf[cur][t - off];
        buf[cur ^ 1][t] = x;
        __syncthreads();
        cur ^= 1;
    }
    if (t < NBUCK) {
        int e = buf[cur][t] - v;
        boff[t] = e;
        bcur[t] = e;
    }
}

// ---------------- bin edges by dst-bucket; packed (src<<7)|dst_low ----------------
__global__ __launch_bounds__(256) void bin_kernel(const int* __restrict__ src,
                                                  const int* __restrict__ dst,
                                                  int* __restrict__ bcur,
                                                  unsigned* __restrict__ binned, int E) {
    __shared__ int h[NBUCK];
    __shared__ int cur[NBUCK];
    for (int i = threadIdx.x; i < NBUCK; i += 256) h[i] = 0;
    __syncthreads();
    int base = blockIdx.x * BIN_CHUNK;
    int end = base + BIN_CHUNK; if (end > E) end = E;
    for (int e = base + threadIdx.x; e < end; e += 256)
        atomicAdd(&h[dst[e] >> BSHIFT], 1);
    __syncthreads();
    for (int i = threadIdx.x; i < NBUCK; i += 256) {
        int c = h[i];
        cur[i] = c ? atomicAdd(&bcur[i], c) : 0;   // reserve contiguous sub-range
    }
    __syncthreads();
    for (int e = base + threadIdx.x; e < end; e += 256) {
        unsigned s = (unsigned)src[e], d = (unsigned)dst[e];
        int pos = atomicAdd(&cur[d >> BSHIFT], 1);
        binned[pos] = (s << BSHIFT) | (d & (BUCKW - 1));
    }
}

// ---------------- degree + dinv from binned edges ----------------
__global__ __launch_bounds__(256) void deg_dinv_kernel(const unsigned* __restrict__ binned,
                                                       const int* __restrict__ bucket_off,
                                                       const int* __restrict__ bucket_cnt,
                                                       int* __restrict__ deg,
                                                       float* __restrict__ dinv, int n) {
    __shared__ int ldeg[BUCKW];
    int b = blockIdx.x;
    for (int i = threadIdx.x; i < BUCKW; i += 256) ldeg[i] = 0;
    __syncthreads();
    int start = bucket_off[b], cnt = bucket_cnt[b];
    for (int k = threadIdx.x; k < cnt; k += 256)
        atomicAdd(&ldeg[binned[start + k] & (BUCKW - 1)], 1);
    __syncthreads();
    int v0 = b << BSHIFT;
    for (int i = threadIdx.x; i < BUCKW; i += 256) {
        int v = v0 + i;
        if (v < n) {
            int dg = ldeg[i];
            deg[v] = dg;
            dinv[v] = rsqrtf((float)dg + 1.0f);   // +1 = self loop
        }
    }
}

// ---------------- node scan (3 phases) ----------------
__global__ void scan1_kernel(const int* __restrict__ cntin, int* __restrict__ excl,
                             int* __restrict__ bsum, int n) {
    __shared__ int buf[2][1024];
    int t = threadIdx.x;
    int gid = blockIdx.x * 1024 + t;
    int v = (gid < n) ? cntin[gid] : 0;
    buf[0][t] = v;
    __syncthreads();
    int cur = 0;
    for (int off = 1; off < 1024; off <<= 1) {
        int x = buf[cur][t];
        if (t >= off) x += buf[cur][t - off];
        buf[cur ^ 1][t] = x;
        __syncthreads();
        cur ^= 1;
    }
    int incl = buf[cur][t];
    if (gid < n) excl[gid] = incl - v;
    if (t == 1023) bsum[blockIdx.x] = incl;
}

__global__ void scan2_kernel(int* __restrict__ bsum, int nb) {
    __shared__ int buf[2][128];
    int t = threadIdx.x;
    int v = (t < nb) ? bsum[t] : 0;
    buf[0][t] = v;
    __syncthreads();
    int cur = 0;
    for (int off = 1; off < 128; off <<= 1) {
        int x = buf[cur][t];
        if (t >= off) x += buf[cur][t - off];
        buf[cur ^ 1][t] = x;
        __syncthreads();
        cur ^= 1;
    }
    if (t < nb) bsum[t] = buf[cur][t] - v;
}

__global__ void scan3_kernel(int* __restrict__ excl, const int* __restrict__ bsum, int n) {
    int gid = blockIdx.x * blockDim.x + threadIdx.x;
    if (gid < n) excl[gid] += bsum[gid >> 10];
}

// ---------------- final CSR placement ----------------
__global__ __launch_bounds__(256) void build2_kernel(const unsigned* __restrict__ binned,
                                                     const int* __restrict__ bucket_off,
                                                     const int* __restrict__ bucket_cnt,
                                                     const int* __restrict__ roff,
                                                     int* __restrict__ csr_src, int n) {
    __shared__ int lcur[BUCKW];
    int b = blockIdx.x;
    int v0 = b << BSHIFT;
    for (int i = threadIdx.x; i < BUCKW; i += 256) {
        int v = v0 + i;
        lcur[i] = (v < n) ? roff[v] : 0;
    }
    __syncthreads();
    int start = bucket_off[b], cnt = bucket_cnt[b];
    for (int k = threadIdx.x; k < cnt; k += 256) {
        unsigned e = binned[start + k];
        int pos = atomicAdd(&lcur[e & (BUCKW - 1)], 1);
        csr_src[pos] = (int)(e >> BSHIFT);
    }
}

// ---------------- prescale layer-1 input: xs = dinv[v] * x[v] (fp32) ----------------
__global__ void prescale_kernel(const float* __restrict__ x, const float* __restrict__ dinv,
                                float* __restrict__ xs, int n) {
    int i = blockIdx.x * blockDim.x + threadIdx.x;   // over n*2 float4s
    if (i >= n * 2) return;
    float dv = dinv[i >> 1];
    float4 v = ((const float4*)x)[i];
    ((float4*)xs)[i] = make_float4(v.x * dv, v.y * dv, v.z * dv, v.w * dv);
}

// ---------------- layer-1 aggregation: fp32 in, fp16 out (FIN=8, G=2) ----------------
__global__ void agg8_kernel(const float* __restrict__ hs, const int* __restrict__ row_off,
                            const int* __restrict__ deg, const float* __restrict__ dinv,
                            const int* __restrict__ csr_src, float2* __restrict__ out, int n) {
    int idx = blockIdx.x * blockDim.x + threadIdx.x;
    if (idx >= n * 2) return;
    int v = idx >> 1;
    int c = idx & 1;
    const float4* h4 = (const float4*)hs;
    float4 acc = h4[(size_t)v * 2 + c];
    int start = row_off[v], cnt = deg[v];
    const int* __restrict__ row = csr_src + start;
    int j = 0;
    for (; j + 8 <= cnt; j += 8) {
        float4 a0 = h4[(size_t)row[j] * 2 + c];
        float4 a1 = h4[(size_t)row[j + 1] * 2 + c];
        float4 a2 = h4[(size_t)row[j + 2] * 2 + c];
        float4 a3 = h4[(size_t)row[j + 3] * 2 + c];
        float4 a4 = h4[(size_t)row[j + 4] * 2 + c];
        float4 a5 = h4[(size_t)row[j + 5] * 2 + c];
        float4 a6 = h4[(size_t)row[j + 6] * 2 + c];
        float4 a7 = h4[(size_t)row[j + 7] * 2 + c];
        acc.x += ((a0.x + a1.x) + (a2.x + a3.x)) + ((a4.x + a5.x) + (a6.x + a7.x));
        acc.y += ((a0.y + a1.y) + (a2.y + a3.y)) + ((a4.y + a5.y) + (a6.y + a7.y));
        acc.z += ((a0.z + a1.z) + (a2.z + a3.z)) + ((a4.z + a5.z) + (a6.z + a7.z));
        acc.w += ((a0.w + a1.w) + (a2.w + a3.w)) + ((a4.w + a5.w) + (a6.w + a7.w));
    }
    for (; j < cnt; ++j) {
        float4 a = h4[(size_t)row[j] * 2 + c];
        acc.x += a.x; acc.y += a.y; acc.z += a.z; acc.w += a.w;
    }
    float dv = dinv[v];
    union { float2 f2; __half2 h2[2]; } u;
    u.h2[0] = __floats2half2_rn(acc.x * dv, acc.y * dv);
    u.h2[1] = __floats2half2_rn(acc.z * dv, acc.w * dv);
    out[idx] = u.f2;        // row = 8 halfs = 2 float2 units
}

// ---------------- fp16 aggregation: out[v] = dinv[v]*(hs[v] + sum_in hs[src]) -----------
template<int FIN>
__global__ void agg_h_kernel(const float4* __restrict__ hs, const int* __restrict__ row_off,
                             const int* __restrict__ deg, const float* __restrict__ dinv,
                             const int* __restrict__ csr_src, float4* __restrict__ out, int n) {
    constexpr int G = FIN / 8;
    int idx = blockIdx.x * blockDim.x + threadIdx.x;
    if (idx >= n * G) return;
    int v = idx / G;
    int c = idx % G;
    float a[8];
    { H8 h; h.f4 = hs[(size_t)v * G + c]; h8_to_f(h, a); }
    int start = row_off[v], cnt = deg[v];
    const int* __restrict__ row = csr_src + start;
    int j = 0;
    for (; j + 8 <= cnt; j += 8) {
        H8 hh[8];
#pragma unroll
        for (int q = 0; q < 8; ++q) hh[q].f4 = hs[(size_t)row[j + q] * G + c];
#pragma unroll
        for (int q = 0; q < 8; ++q) {
            float f[8]; h8_to_f(hh[q], f);
#pragma unroll
            for (int k = 0; k < 8; ++k) a[k] += f[k];
        }
    }
    for (; j + 4 <= cnt; j += 4) {
        H8 h0, h1, h2, h3;
        h0.f4 = hs[(size_t)row[j] * G + c];
        h1.f4 = hs[(size_t)row[j + 1] * G + c];
        h2.f4 = hs[(size_t)row[j + 2] * G + c];
        h3.f4 = hs[(size_t)row[j + 3] * G + c];
        float f0[8], f1[8], f2[8], f3[8];
        h8_to_f(h0, f0); h8_to_f(h1, f1); h8_to_f(h2, f2); h8_to_f(h3, f3);
#pragma unroll
        for (int k = 0; k < 8; ++k) a[k] += (f0[k] + f1[k]) + (f2[k] + f3[k]);
    }
    for (; j < cnt; ++j) {
        H8 h; h.f4 = hs[(size_t)row[j] * G + c];
        float f[8]; h8_to_f(h, f);
#pragma unroll
        for (int k = 0; k < 8; ++k) a[k] += f[k];
    }
    float dv = dinv[v];
#pragma unroll
    for (int k = 0; k < 8; ++k) a[k] *= dv;
    H8 o = f_to_h8(a);
    out[(size_t)v * G + c] = o.f4;
}

// ---------------- fused matmul + bias + prelu; fp16 in/out, fp32 math ----------------
template<int FIN, int FOUT, bool SCALE>
__global__ __launch_bounds__(256) void matmul_kernel(
    const float4* __restrict__ tin, const float* __restrict__ W,
    const float* __restrict__ bias, const float* __restrict__ slope,
    const float* __restrict__ dinv, float2* __restrict__ hout, int n) {
    constexpr int TPN = FOUT / 4;            // threads per node (4 outputs each)
    constexpr int NPB = (256 / TPN) * 4;     // nodes per block
    __shared__ float4 Wl[FIN * TPN];
    const float4* Wg = (const float4*)W;
    for (int i = threadIdx.x; i < FIN * TPN; i += 256) Wl[i] = Wg[i];
    __syncthreads();
    int t = threadIdx.x;
    int grp = t / TPN;
    int f4 = t % TPN;
    int v0 = blockIdx.x * NPB + grp * 4;
    float s = slope ? *slope : 1.0f;
    float4 bv = ((const float4*)bias)[f4];
    float4 acc[4];
#pragma unroll
    for (int nn = 0; nn < 4; ++nn) acc[nn] = bv;
#pragma unroll
    for (int i = 0; i < FIN; i += 8) {
        float r[4][8];
#pragma unroll
        for (int nn = 0; nn < 4; ++nn) {
            int v = v0 + nn;
            H8 h;
            h.f4 = (v < n) ? tin[(size_t)v * (FIN / 8) + (i >> 3)]
                           : make_float4(0.f, 0.f, 0.f, 0.f);
            h8_to_f(h, r[nn]);
        }
#pragma unroll
        for (int k = 0; k < 8; ++k) {
            float4 wv = Wl[(i + k) * TPN + f4];
#pragma unroll
            for (int nn = 0; nn < 4; ++nn) {
                float rk = r[nn][k];
                acc[nn].x += wv.x * rk;
                acc[nn].y += wv.y * rk;
                acc[nn].z += wv.z * rk;
                acc[nn].w += wv.w * rk;
            }
        }
    }
#pragma unroll
    for (int nn = 0; nn < 4; ++nn) {
        int v = v0 + nn;
        if (v < n) {
            float m = SCALE ? dinv[v] : 1.0f;
            float ox = (fmaxf(acc[nn].x, 0.f) + s * fminf(acc[nn].x, 0.f)) * m;
            float oy = (fmaxf(acc[nn].y, 0.f) + s * fminf(acc[nn].y, 0.f)) * m;
            float oz = (fmaxf(acc[nn].z, 0.f) + s * fminf(acc[nn].z, 0.f)) * m;
            float ow = (fmaxf(acc[nn].w, 0.f) + s * fminf(acc[nn].w, 0.f)) * m;
            union { float2 f2; __half2 h2[2]; } u;
            u.h2[0] = __floats2half2_rn(ox, oy);
            u.h2[1] = __floats2half2_rn(oz, ow);
            hout[(size_t)v * TPN + f4] = u.f2;   // row = FOUT halfs = TPN float2s
        }
    }
}

// ---------------- makeM: M = W4 @ Wlin (64x4), bb = b4 @ Wlin + blin ----------------
__global__ __launch_bounds__(256) void makeM_kernel(
    const float* __restrict__ W4, const float* __restrict__ b4,
    const float* __restrict__ Wlin, const float* __restrict__ blin,
    float* __restrict__ M, float* __restrict__ bb) {
    int t = threadIdx.x;          // 256 = 64 * 4
    int k = t >> 2, c = t & 3;
    float m = 0.f;
    for (int j = 0; j < 128; ++j) m += W4[k * 128 + j] * Wlin[j * 4 + c];
    M[k * 4 + c] = m;
    if (t < 4) {
        float v = blin[t];
        for (int j = 0; j < 128; ++j) v += b4[j] * Wlin[j * 4 + t];
        bb[t] = v;
    }
}

// ---------------- layer-3 matmul fused with z-projection: z[v] = prelu-row @ M --------
// Same compute as matmul<32,64,true> but instead of storing the fp16 row,
// each thread's 4 outputs are projected through M and LDS-reduced per node.
__global__ __launch_bounds__(256) void matmul_z_kernel(
    const float4* __restrict__ tin, const float* __restrict__ W,
    const float* __restrict__ bias, const float* __restrict__ slope,
    const float* __restrict__ dinv, const float* __restrict__ M,
    float4* __restrict__ z, int n) {
    constexpr int FIN = 32, FOUT = 64, TPN = FOUT / 4, NPB = 64;
    __shared__ float4 Wl[FIN * TPN];           // 8 KB
    __shared__ float4 Ml[FOUT];                // 1 KB  (row f -> M[f][0..3])
    __shared__ float zacc[NPB * 4];            // 1 KB
    const float4* Wg = (const float4*)W;
    for (int i = threadIdx.x; i < FIN * TPN; i += 256) Wl[i] = Wg[i];
    if (threadIdx.x < FOUT) Ml[threadIdx.x] = ((const float4*)M)[threadIdx.x];
    for (int i = threadIdx.x; i < NPB * 4; i += 256) zacc[i] = 0.f;
    __syncthreads();
    int t = threadIdx.x;
    int grp = t / TPN;
    int f4 = t % TPN;
    int v0 = blockIdx.x * NPB + grp * 4;
    float s = *slope;
    float4 bv = ((const float4*)bias)[f4];
    float4 acc[4];
#pragma unroll
    for (int nn = 0; nn < 4; ++nn) acc[nn] = bv;
#pragma unroll
    for (int i = 0; i < FIN; i += 8) {
        float r[4][8];
#pragma unroll
        for (int nn = 0; nn < 4; ++nn) {
            int v = v0 + nn;
            H8 h;
            h.f4 = (v < n) ? tin[(size_t)v * (FIN / 8) + (i >> 3)]
                           : make_float4(0.f, 0.f, 0.f, 0.f);
            h8_to_f(h, r[nn]);
        }
#pragma unroll
        for (int k = 0; k < 8; ++k) {
            float4 wv = Wl[(i + k) * TPN + f4];
#pragma unroll
            for (int nn = 0; nn < 4; ++nn) {
                float rk = r[nn][k];
                acc[nn].x += wv.x * rk;
                acc[nn].y += wv.y * rk;
                acc[nn].z += wv.z * rk;
                acc[nn].w += wv.w * rk;
            }
        }
    }
    // epilogue: prelu * dinv, project through M, LDS-reduce per node
    float4 m0 = Ml[f4 * 4 + 0];
    float4 m1 = Ml[f4 * 4 + 1];
    float4 m2 = Ml[f4 * 4 + 2];
    float4 m3 = Ml[f4 * 4 + 3];
#pragma unroll
    for (int nn = 0; nn < 4; ++nn) {
        int v = v0 + nn;
        if (v < n) {
            float dvm = dinv[v];
            float ox = (fmaxf(acc[nn].x, 0.f) + s * fminf(acc[nn].x, 0.f)) * dvm;
            float oy = (fmaxf(acc[nn].y, 0.f) + s * fminf(acc[nn].y, 0.f)) * dvm;
            float oz = (fmaxf(acc[nn].z, 0.f) + s * fminf(acc[nn].z, 0.f)) * dvm;
            float ow = (fmaxf(acc[nn].w, 0.f) + s * fminf(acc[nn].w, 0.f)) * dvm;
            float px = ox * m0.x + oy * m1.x + oz * m2.x + ow * m3.x;
            float py = ox * m0.y + oy * m1.y + oz * m2.y + ow * m3.y;
            float pz = ox * m0.z + oy * m1.z + oz * m2.z + ow * m3.z;
            float pw = ox * m0.w + oy * m1.w + oz * m2.w + ow * m3.w;
            float* zp = &zacc[(grp * 4 + nn) * 4];
            atomicAdd(zp + 0, px); atomicAdd(zp + 1, py);
            atomicAdd(zp + 2, pz); atomicAdd(zp + 3, pw);
        }
    }
    __syncthreads();
    if (t < NPB) {
        int v = blockIdx.x * NPB + t;
        if (v < n)
            z[v] = make_float4(zacc[t * 4], zacc[t * 4 + 1], zacc[t * 4 + 2], zacc[t * 4 + 3]);
    }
}

// ---------------- layer-4 aggregation + pooling in z-space (4-dim, L2-resident) --------
__global__ __launch_bounds__(256) void aggpool4_kernel(
    const float4* __restrict__ z, const int* __restrict__ row_off,
    const int* __restrict__ deg, const float* __restrict__ dinv,
    const int* __restrict__ csr_src, const int* __restrict__ batch,
    float* __restrict__ sums, float* __restrict__ cnt, int n) {
    __shared__ float lacc[NG * 4];
    __shared__ float lcnt[NG];
    int tid = threadIdx.x;
    if (tid < NG * 4) lacc[tid] = 0.f;
    if (tid < NG) lcnt[tid] = 0.f;
    __syncthreads();
    int v = blockIdx.x * 256 + tid;
    if (v < n) {
        float4 acc = z[v];
        int start = row_off[v], dcnt = deg[v];
        const int* __restrict__ row = csr_src + start;
        int j = 0;
        for (; j + 4 <= dcnt; j += 4) {
            float4 a0 = z[row[j]];
            float4 a1 = z[row[j + 1]];
            float4 a2 = z[row[j + 2]];
            float4 a3 = z[row[j + 3]];
            acc.x += (a0.x + a1.x) + (a2.x + a3.x);
            acc.y += (a0.y + a1.y) + (a2.y + a3.y);
            acc.z += (a0.z + a1.z) + (a2.z + a3.z);
            acc.w += (a0.w + a1.w) + (a2.w + a3.w);
        }
        for (; j < dcnt; ++j) {
            float4 a = z[row[j]];
            acc.x += a.x; acc.y += a.y; acc.z += a.z; acc.w += a.w;
        }
        float dv = dinv[v];
        int g = batch[v];
        float* lp = &lacc[g * 4];
        atomicAdd(lp + 0, acc.x * dv); atomicAdd(lp + 1, acc.y * dv);
        atomicAdd(lp + 2, acc.z * dv); atomicAdd(lp + 3, acc.w * dv);
        atomicAdd(&lcnt[g], 1.f);
    }
    __syncthreads();
    if (tid < NG * 4) {
        float val = lacc[tid];
        if (val != 0.f) atomicAdd(&sums[tid], val);
    }
    if (tid < NG) {
        float val = lcnt[tid];
        if (val != 0.f) atomicAdd(&cnt[tid], val);
    }
}

// ---------------- head: out[g][c] = sums[g][c]/cnt[g] + bb[c] ----------------
__global__ void head_kernel(const float* __restrict__ sums, const float* __restrict__ cnt,
                            const float* __restrict__ bb, float* __restrict__ out) {
    int t = threadIdx.x;          // 256 = 64 graphs * 4 classes
    int g = t >> 2, c = t & 3;
    out[t] = sums[t] / fmaxf(cnt[g], 1.f) + bb[c];
}

extern "C" void kernel_launch(void* const* d_in, const int* in_sizes, int n_in,
                              void* d_out, int out_size, void* d_ws, size_t ws_size,
                              hipStream_t stream) {
    const float* x    = (const float*)d_in[0];
    const int* esrc   = (const int*)d_in[1];
    const int* edst   = (const int*)d_in[2];
    const int* batch  = (const int*)d_in[3];
    const float* W1 = (const float*)d_in[4],  *b1 = (const float*)d_in[5];
    const float* W2 = (const float*)d_in[6],  *b2 = (const float*)d_in[7];
    const float* W3 = (const float*)d_in[8],  *b3 = (const float*)d_in[9];
    const float* W4 = (const float*)d_in[10], *b4 = (const float*)d_in[11];
    const float* a1 = (const float*)d_in[12];
    const float* a2 = (const float*)d_in[13];
    const float* a3 = (const float*)d_in[14];
    const float* Wlin = (const float*)d_in[15], *blin = (const float*)d_in[16];
    float* out = (float*)d_out;

    const int N = NN, E = NE;
    const int NB = (N + 1023) / 1024;                   // node-scan blocks (98)
    const int NBIN = (E + BIN_CHUNK - 1) / BIN_CHUNK;   // 196

    // workspace carve-up
    char* w = (char*)d_ws;
    size_t off = 0;
    auto alloc = [&](size_t bytes) { size_t r = off; off += (bytes + 255) & ~(size_t)255; return r; };
    size_t o_bcnt = alloc((size_t)NBUCK * 4);      // needs zero
    size_t o_pool = alloc((size_t)NG * 4 * 4);     // needs zero (pooled z sums)
    size_t o_cnt  = alloc((size_t)NG * 4);         // needs zero
    size_t zero_bytes = off;
    size_t o_deg  = alloc((size_t)N * 4);
    size_t o_dinv = alloc((size_t)N * 4);
    size_t o_roff = alloc((size_t)N * 4);
    size_t o_boff = alloc((size_t)NBUCK * 4);
    size_t o_bcur = alloc((size_t)NBUCK * 4);
    size_t o_bsum = alloc((size_t)128 * 4);
    size_t o_csrc = alloc((size_t)E * 4);
    size_t o_bin  = alloc((size_t)E * 4);          // packed (src<<7)|dst_low
    size_t o_X    = alloc((size_t)N * 8 * 4);      // prescaled x (fp32)
    size_t o_A    = alloc((size_t)N * 32 * 2);     // activations fp16 (max 32 halfs now)
    size_t o_T    = alloc((size_t)N * 32 * 2);     // agg output fp16 (max 32 halfs)
    size_t o_z    = alloc((size_t)N * 4 * 4);      // z projections (float4/node)
    size_t o_M    = alloc((size_t)64 * 4 * 4);     // W4@Wlin
    size_t o_bb   = alloc((size_t)4 * 4);          // b4@Wlin + blin
    (void)ws_size;
    int*      bcnt   = (int*)(w + o_bcnt);
    float*    pool   = (float*)(w + o_pool);
    float*    cnt    = (float*)(w + o_cnt);
    int*      deg    = (int*)(w + o_deg);
    float*    dinv   = (float*)(w + o_dinv);
    int*      roff   = (int*)(w + o_roff);
    int*      boff   = (int*)(w + o_boff);
    int*      bcur   = (int*)(w + o_bcur);
    int*      bsum   = (int*)(w + o_bsum);
    int*      csrc   = (int*)(w + o_csrc);
    unsigned* binned = (unsigned*)(w + o_bin);
    float*    XS     = (float*)(w + o_X);
    char*     A      = (char*)(w + o_A);
    char*     T      = (char*)(w + o_T);
    float4*   z      = (float4*)(w + o_z);
    float*    M      = (float*)(w + o_M);
    float*    bb     = (float*)(w + o_bb);

    hipMemsetAsync(w, 0, zero_bytes, stream);

    // ---- head constants (independent; launch early) ----
    makeM_kernel<<<1, 256, 0, stream>>>(W4, b4, Wlin, blin, M, bb);

    // ---- CSR build via dst-bucket binning (once, reused by all 4 layers) ----
    bucket_hist_kernel<<<256, 256, 0, stream>>>(edst, bcnt, E);
    bucket_scan_kernel<<<1, 1024, 0, stream>>>(bcnt, boff, bcur);
    bin_kernel<<<NBIN, 256, 0, stream>>>(esrc, edst, bcur, binned, E);
    deg_dinv_kernel<<<NBUCK, 256, 0, stream>>>(binned, boff, bcnt, deg, dinv, N);
    scan1_kernel<<<NB, 1024, 0, stream>>>(deg, roff, bsum, N);
    scan2_kernel<<<1, 128, 0, stream>>>(bsum, NB);
    scan3_kernel<<<(N + 255) / 256, 256, 0, stream>>>(roff, bsum, N);
    build2_kernel<<<NBUCK, 256, 0, stream>>>(binned, boff, bcnt, roff, csrc, N);

    // ---- layer 1: agg(dinv*x)[8] @ W1 -> 16, prelu a1, output pre-scaled (fp16) ----
    prescale_kernel<<<(N * 2 + 255) / 256, 256, 0, stream>>>(x, dinv, XS, N);
    agg8_kernel<<<(N * 2 + 255) / 256, 256, 0, stream>>>(XS, roff, deg, dinv, csrc, (float2*)T, N);
    matmul_kernel<8, 16, true><<<(N + 255) / 256, 256, 0, stream>>>(
        (const float4*)T, W1, b1, a1, dinv, (float2*)A, N);

    // ---- layer 2 ----
    agg_h_kernel<16><<<(N * 2 + 255) / 256, 256, 0, stream>>>(
        (const float4*)A, roff, deg, dinv, csrc, (float4*)T, N);
    matmul_kernel<16, 32, true><<<(N + 127) / 128, 256, 0, stream>>>(
        (const float4*)T, W2, b2, a2, dinv, (float2*)A, N);

    // ---- layer 3: agg -> matmul_z (z = dinv*prelu(row) @ M; A never materialized) ----
    agg_h_kernel<32><<<(N * 4 + 255) / 256, 256, 0, stream>>>(
        (const float4*)A, roff, deg, dinv, csrc, (float4*)T, N);
    matmul_z_kernel<<<(N + 63) / 64, 256, 0, stream>>>(
        (const float4*)T, W3, b3, a3, dinv, M, z, N);

    // ---- layer 4 in z-space: gather-aggregate + pool over N x 4 (L2-resident) ----
    aggpool4_kernel<<<(N + 255) / 256, 256, 0, stream>>>(
        z, roff, deg, dinv, csrc, batch, pool, cnt, N);
    head_kernel<<<1, 256, 0, stream>>>(pool, cnt, bb, out);
}

// Round 13
// 265.025 us; speedup vs baseline: 1.1548x; 1.1548x over previous
//
#include <hip/hip_runtime.h>
#include <hip/hip_fp16.h>

// Problem constants (match reference file)
#define NN 100000
#define NE 1600000
#define NG 64

// dst-bucketing for the CSR build
#define BSHIFT 7
#define BUCKW (1 << BSHIFT)                 // 128 nodes per bucket
#define NBUCK ((NN + BUCKW - 1) >> BSHIFT)  // 782
#define BIN_CHUNK 8192

// ---- fp16 8-wide helpers (activations stored fp16, math in fp32) ----
union H8 { float4 f4; __half2 h2[4]; };
__device__ __forceinline__ void h8_to_f(const H8& h, float* f) {
    float2 a = __half22float2(h.h2[0]);
    float2 b = __half22float2(h.h2[1]);
    float2 c = __half22float2(h.h2[2]);
    float2 d = __half22float2(h.h2[3]);
    f[0]=a.x; f[1]=a.y; f[2]=b.x; f[3]=b.y; f[4]=c.x; f[5]=c.y; f[6]=d.x; f[7]=d.y;
}
__device__ __forceinline__ H8 f_to_h8(const float* f) {
    H8 h;
    h.h2[0] = __floats2half2_rn(f[0], f[1]);
    h.h2[1] = __floats2half2_rn(f[2], f[3]);
    h.h2[2] = __floats2half2_rn(f[4], f[5]);
    h.h2[3] = __floats2half2_rn(f[6], f[7]);
    return h;
}

// ---------------- bucket histogram (LDS-aggregated) ----------------
__global__ __launch_bounds__(256) void bucket_hist_kernel(const int* __restrict__ dst,
                                                          int* __restrict__ bucket_cnt, int E) {
    __shared__ int h[NBUCK];
    for (int i = threadIdx.x; i < NBUCK; i += 256) h[i] = 0;
    __syncthreads();
    int stride = gridDim.x * 256;
    for (int e = blockIdx.x * 256 + threadIdx.x; e < E; e += stride)
        atomicAdd(&h[dst[e] >> BSHIFT], 1);
    __syncthreads();
    for (int i = threadIdx.x; i < NBUCK; i += 256)
        if (h[i]) atomicAdd(&bucket_cnt[i], h[i]);
}

// ---------------- bucket scan: single block ----------------
__global__ void bucket_scan_kernel(const int* __restrict__ bcnt, int* __restrict__ boff,
                                   int* __restrict__ bcur) {
    __shared__ int buf[2][1024];
    int t = threadIdx.x;
    int v = (t < NBUCK) ? bcnt[t] : 0;
    buf[0][t] = v;
    __syncthreads();
    int cur = 0;
    for (int off = 1; off < 1024; off <<= 1) {
        int x = buf[cur][t];
        if (t >= off) x += buf[cur][t - off];
        buf[cur ^ 1][t] = x;
        __syncthreads();
        cur ^= 1;
    }
    if (t < NBUCK) {
        int e = buf[cur][t] - v;
        boff[t] = e;
        bcur[t] = e;
    }
}

// ---------------- bin edges by dst-bucket; packed (src<<7)|dst_low ----------------
__global__ __launch_bounds__(256) void bin_kernel(const int* __restrict__ src,
                                                  const int* __restrict__ dst,
                                                  int* __restrict__ bcur,
                                                  unsigned* __restrict__ binned, int E) {
    __shared__ int h[NBUCK];
    __shared__ int cur[NBUCK];
    for (int i = threadIdx.x; i < NBUCK; i += 256) h[i] = 0;
    __syncthreads();
    int base = blockIdx.x * BIN_CHUNK;
    int end = base + BIN_CHUNK; if (end > E) end = E;
    for (int e = base + threadIdx.x; e < end; e += 256)
        atomicAdd(&h[dst[e] >> BSHIFT], 1);
    __syncthreads();
    for (int i = threadIdx.x; i < NBUCK; i += 256) {
        int c = h[i];
        cur[i] = c ? atomicAdd(&bcur[i], c) : 0;   // reserve contiguous sub-range
    }
    __syncthreads();
    for (int e = base + threadIdx.x; e < end; e += 256) {
        unsigned s = (unsigned)src[e], d = (unsigned)dst[e];
        int pos = atomicAdd(&cur[d >> BSHIFT], 1);
        binned[pos] = (s << BSHIFT) | (d & (BUCKW - 1));
    }
}

// ---------------- degree + dinv from binned edges ----------------
__global__ __launch_bounds__(256) void deg_dinv_kernel(const unsigned* __restrict__ binned,
                                                       const int* __restrict__ bucket_off,
                                                       const int* __restrict__ bucket_cnt,
                                                       int* __restrict__ deg,
                                                       float* __restrict__ dinv, int n) {
    __shared__ int ldeg[BUCKW];
    int b = blockIdx.x;
    for (int i = threadIdx.x; i < BUCKW; i += 256) ldeg[i] = 0;
    __syncthreads();
    int start = bucket_off[b], cnt = bucket_cnt[b];
    for (int k = threadIdx.x; k < cnt; k += 256)
        atomicAdd(&ldeg[binned[start + k] & (BUCKW - 1)], 1);
    __syncthreads();
    int v0 = b << BSHIFT;
    for (int i = threadIdx.x; i < BUCKW; i += 256) {
        int v = v0 + i;
        if (v < n) {
            int dg = ldeg[i];
            deg[v] = dg;
            dinv[v] = rsqrtf((float)dg + 1.0f);   // +1 = self loop
        }
    }
}

// ---------------- node scan (3 phases) ----------------
__global__ void scan1_kernel(const int* __restrict__ cntin, int* __restrict__ excl,
                             int* __restrict__ bsum, int n) {
    __shared__ int buf[2][1024];
    int t = threadIdx.x;
    int gid = blockIdx.x * 1024 + t;
    int v = (gid < n) ? cntin[gid] : 0;
    buf[0][t] = v;
    __syncthreads();
    int cur = 0;
    for (int off = 1; off < 1024; off <<= 1) {
        int x = buf[cur][t];
        if (t >= off) x += buf[cur][t - off];
        buf[cur ^ 1][t] = x;
        __syncthreads();
        cur ^= 1;
    }
    int incl = buf[cur][t];
    if (gid < n) excl[gid] = incl - v;
    if (t == 1023) bsum[blockIdx.x] = incl;
}

__global__ void scan2_kernel(int* __restrict__ bsum, int nb) {
    __shared__ int buf[2][128];
    int t = threadIdx.x;
    int v = (t < nb) ? bsum[t] : 0;
    buf[0][t] = v;
    __syncthreads();
    int cur = 0;
    for (int off = 1; off < 128; off <<= 1) {
        int x = buf[cur][t];
        if (t >= off) x += buf[cur][t - off];
        buf[cur ^ 1][t] = x;
        __syncthreads();
        cur ^= 1;
    }
    if (t < nb) bsum[t] = buf[cur][t] - v;
}

__global__ void scan3_kernel(int* __restrict__ excl, const int* __restrict__ bsum, int n) {
    int gid = blockIdx.x * blockDim.x + threadIdx.x;
    if (gid < n) excl[gid] += bsum[gid >> 10];
}

// ---------------- final CSR placement ----------------
__global__ __launch_bounds__(256) void build2_kernel(const unsigned* __restrict__ binned,
                                                     const int* __restrict__ bucket_off,
                                                     const int* __restrict__ bucket_cnt,
                                                     const int* __restrict__ roff,
                                                     int* __restrict__ csr_src, int n) {
    __shared__ int lcur[BUCKW];
    int b = blockIdx.x;
    int v0 = b << BSHIFT;
    for (int i = threadIdx.x; i < BUCKW; i += 256) {
        int v = v0 + i;
        lcur[i] = (v < n) ? roff[v] : 0;
    }
    __syncthreads();
    int start = bucket_off[b], cnt = bucket_cnt[b];
    for (int k = threadIdx.x; k < cnt; k += 256) {
        unsigned e = binned[start + k];
        int pos = atomicAdd(&lcur[e & (BUCKW - 1)], 1);
        csr_src[pos] = (int)(e >> BSHIFT);
    }
}

// ---------------- prescale layer-1 input: xs = dinv[v] * x[v] (fp32) ----------------
__global__ void prescale_kernel(const float* __restrict__ x, const float* __restrict__ dinv,
                                float* __restrict__ xs, int n) {
    int i = blockIdx.x * blockDim.x + threadIdx.x;   // over n*2 float4s
    if (i >= n * 2) return;
    float dv = dinv[i >> 1];
    float4 v = ((const float4*)x)[i];
    ((float4*)xs)[i] = make_float4(v.x * dv, v.y * dv, v.z * dv, v.w * dv);
}

// ---------------- layer-1 aggregation: fp32 in, fp16 out (FIN=8, G=2) ----------------
__global__ void agg8_kernel(const float* __restrict__ hs, const int* __restrict__ row_off,
                            const int* __restrict__ deg, const float* __restrict__ dinv,
                            const int* __restrict__ csr_src, float2* __restrict__ out, int n) {
    int idx = blockIdx.x * blockDim.x + threadIdx.x;
    if (idx >= n * 2) return;
    int v = idx >> 1;
    int c = idx & 1;
    const float4* h4 = (const float4*)hs;
    float4 acc = h4[(size_t)v * 2 + c];
    int start = row_off[v], cnt = deg[v];
    const int* __restrict__ row = csr_src + start;
    int j = 0;
    for (; j + 8 <= cnt; j += 8) {
        float4 a0 = h4[(size_t)row[j] * 2 + c];
        float4 a1 = h4[(size_t)row[j + 1] * 2 + c];
        float4 a2 = h4[(size_t)row[j + 2] * 2 + c];
        float4 a3 = h4[(size_t)row[j + 3] * 2 + c];
        float4 a4 = h4[(size_t)row[j + 4] * 2 + c];
        float4 a5 = h4[(size_t)row[j + 5] * 2 + c];
        float4 a6 = h4[(size_t)row[j + 6] * 2 + c];
        float4 a7 = h4[(size_t)row[j + 7] * 2 + c];
        acc.x += ((a0.x + a1.x) + (a2.x + a3.x)) + ((a4.x + a5.x) + (a6.x + a7.x));
        acc.y += ((a0.y + a1.y) + (a2.y + a3.y)) + ((a4.y + a5.y) + (a6.y + a7.y));
        acc.z += ((a0.z + a1.z) + (a2.z + a3.z)) + ((a4.z + a5.z) + (a6.z + a7.z));
        acc.w += ((a0.w + a1.w) + (a2.w + a3.w)) + ((a4.w + a5.w) + (a6.w + a7.w));
    }
    for (; j < cnt; ++j) {
        float4 a = h4[(size_t)row[j] * 2 + c];
        acc.x += a.x; acc.y += a.y; acc.z += a.z; acc.w += a.w;
    }
    float dv = dinv[v];
    union { float2 f2; __half2 h2[2]; } u;
    u.h2[0] = __floats2half2_rn(acc.x * dv, acc.y * dv);
    u.h2[1] = __floats2half2_rn(acc.z * dv, acc.w * dv);
    out[idx] = u.f2;        // row = 8 halfs = 2 float2 units
}

// ---------------- fp16 aggregation: out[v] = dinv[v]*(hs[v] + sum_in hs[src]) -----------
template<int FIN>
__global__ void agg_h_kernel(const float4* __restrict__ hs, const int* __restrict__ row_off,
                             const int* __restrict__ deg, const float* __restrict__ dinv,
                             const int* __restrict__ csr_src, float4* __restrict__ out, int n) {
    constexpr int G = FIN / 8;
    int idx = blockIdx.x * blockDim.x + threadIdx.x;
    if (idx >= n * G) return;
    int v = idx / G;
    int c = idx % G;
    float a[8];
    { H8 h; h.f4 = hs[(size_t)v * G + c]; h8_to_f(h, a); }
    int start = row_off[v], cnt = deg[v];
    const int* __restrict__ row = csr_src + start;
    int j = 0;
    for (; j + 8 <= cnt; j += 8) {
        H8 hh[8];
#pragma unroll
        for (int q = 0; q < 8; ++q) hh[q].f4 = hs[(size_t)row[j + q] * G + c];
#pragma unroll
        for (int q = 0; q < 8; ++q) {
            float f[8]; h8_to_f(hh[q], f);
#pragma unroll
            for (int k = 0; k < 8; ++k) a[k] += f[k];
        }
    }
    for (; j + 4 <= cnt; j += 4) {
        H8 h0, h1, h2, h3;
        h0.f4 = hs[(size_t)row[j] * G + c];
        h1.f4 = hs[(size_t)row[j + 1] * G + c];
        h2.f4 = hs[(size_t)row[j + 2] * G + c];
        h3.f4 = hs[(size_t)row[j + 3] * G + c];
        float f0[8], f1[8], f2[8], f3[8];
        h8_to_f(h0, f0); h8_to_f(h1, f1); h8_to_f(h2, f2); h8_to_f(h3, f3);
#pragma unroll
        for (int k = 0; k < 8; ++k) a[k] += (f0[k] + f1[k]) + (f2[k] + f3[k]);
    }
    for (; j < cnt; ++j) {
        H8 h; h.f4 = hs[(size_t)row[j] * G + c];
        float f[8]; h8_to_f(h, f);
#pragma unroll
        for (int k = 0; k < 8; ++k) a[k] += f[k];
    }
    float dv = dinv[v];
#pragma unroll
    for (int k = 0; k < 8; ++k) a[k] *= dv;
    H8 o = f_to_h8(a);
    out[(size_t)v * G + c] = o.f4;
}

// ---------------- fused matmul + bias + prelu; fp16 in/out, fp32 math ----------------
template<int FIN, int FOUT, bool SCALE>
__global__ __launch_bounds__(256) void matmul_kernel(
    const float4* __restrict__ tin, const float* __restrict__ W,
    const float* __restrict__ bias, const float* __restrict__ slope,
    const float* __restrict__ dinv, float2* __restrict__ hout, int n) {
    constexpr int TPN = FOUT / 4;            // threads per node (4 outputs each)
    constexpr int NPB = (256 / TPN) * 4;     // nodes per block
    __shared__ float4 Wl[FIN * TPN];
    const float4* Wg = (const float4*)W;
    for (int i = threadIdx.x; i < FIN * TPN; i += 256) Wl[i] = Wg[i];
    __syncthreads();
    int t = threadIdx.x;
    int grp = t / TPN;
    int f4 = t % TPN;
    int v0 = blockIdx.x * NPB + grp * 4;
    float s = slope ? *slope : 1.0f;
    float4 bv = ((const float4*)bias)[f4];
    float4 acc[4];
#pragma unroll
    for (int nn = 0; nn < 4; ++nn) acc[nn] = bv;
#pragma unroll
    for (int i = 0; i < FIN; i += 8) {
        float r[4][8];
#pragma unroll
        for (int nn = 0; nn < 4; ++nn) {
            int v = v0 + nn;
            H8 h;
            h.f4 = (v < n) ? tin[(size_t)v * (FIN / 8) + (i >> 3)]
                           : make_float4(0.f, 0.f, 0.f, 0.f);
            h8_to_f(h, r[nn]);
        }
#pragma unroll
        for (int k = 0; k < 8; ++k) {
            float4 wv = Wl[(i + k) * TPN + f4];
#pragma unroll
            for (int nn = 0; nn < 4; ++nn) {
                float rk = r[nn][k];
                acc[nn].x += wv.x * rk;
                acc[nn].y += wv.y * rk;
                acc[nn].z += wv.z * rk;
                acc[nn].w += wv.w * rk;
            }
        }
    }
#pragma unroll
    for (int nn = 0; nn < 4; ++nn) {
        int v = v0 + nn;
        if (v < n) {
            float m = SCALE ? dinv[v] : 1.0f;
            float ox = (fmaxf(acc[nn].x, 0.f) + s * fminf(acc[nn].x, 0.f)) * m;
            float oy = (fmaxf(acc[nn].y, 0.f) + s * fminf(acc[nn].y, 0.f)) * m;
            float oz = (fmaxf(acc[nn].z, 0.f) + s * fminf(acc[nn].z, 0.f)) * m;
            float ow = (fmaxf(acc[nn].w, 0.f) + s * fminf(acc[nn].w, 0.f)) * m;
            union { float2 f2; __half2 h2[2]; } u;
            u.h2[0] = __floats2half2_rn(ox, oy);
            u.h2[1] = __floats2half2_rn(oz, ow);
            hout[(size_t)v * TPN + f4] = u.f2;   // row = FOUT halfs = TPN float2s
        }
    }
}

// ---------------- makeM: M = W4 @ Wlin (64x4), bb = b4 @ Wlin + blin ----------------
__global__ __launch_bounds__(256) void makeM_kernel(
    const float* __restrict__ W4, const float* __restrict__ b4,
    const float* __restrict__ Wlin, const float* __restrict__ blin,
    float* __restrict__ M, float* __restrict__ bb) {
    int t = threadIdx.x;          // 256 = 64 * 4
    int k = t >> 2, c = t & 3;
    float m = 0.f;
    for (int j = 0; j < 128; ++j) m += W4[k * 128 + j] * Wlin[j * 4 + c];
    M[k * 4 + c] = m;
    if (t < 4) {
        float v = blin[t];
        for (int j = 0; j < 128; ++j) v += b4[j] * Wlin[j * 4 + t];
        bb[t] = v;
    }
}

// ---------------- layer-3 matmul fused with z-projection (shuffle-reduced) ------------
// z[v] = (dinv*prelu(row)) @ M. The 16 threads of a node are contiguous lanes in a wave;
// reduce their 4-component partials with __shfl_xor over width 16 (no LDS, no atomics).
__global__ __launch_bounds__(256) void matmul_z_kernel(
    const float4* __restrict__ tin, const float* __restrict__ W,
    const float* __restrict__ bias, const float* __restrict__ slope,
    const float* __restrict__ dinv, const float* __restrict__ M,
    float4* __restrict__ z, int n) {
    constexpr int FIN = 32, FOUT = 64, TPN = FOUT / 4, NPB = 64;
    __shared__ float4 Wl[FIN * TPN];           // 8 KB
    __shared__ float4 Ml[FOUT];                // 1 KB  (row f -> M[f][0..3])
    const float4* Wg = (const float4*)W;
    for (int i = threadIdx.x; i < FIN * TPN; i += 256) Wl[i] = Wg[i];
    if (threadIdx.x < FOUT) Ml[threadIdx.x] = ((const float4*)M)[threadIdx.x];
    __syncthreads();
    int t = threadIdx.x;
    int grp = t / TPN;
    int f4 = t % TPN;
    int v0 = blockIdx.x * NPB + grp * 4;
    float s = *slope;
    float4 bv = ((const float4*)bias)[f4];
    float4 acc[4];
#pragma unroll
    for (int nn = 0; nn < 4; ++nn) acc[nn] = bv;
#pragma unroll
    for (int i = 0; i < FIN; i += 8) {
        float r[4][8];
#pragma unroll
        for (int nn = 0; nn < 4; ++nn) {
            int v = v0 + nn;
            H8 h;
            h.f4 = (v < n) ? tin[(size_t)v * (FIN / 8) + (i >> 3)]
                           : make_float4(0.f, 0.f, 0.f, 0.f);
            h8_to_f(h, r[nn]);
        }
#pragma unroll
        for (int k = 0; k < 8; ++k) {
            float4 wv = Wl[(i + k) * TPN + f4];
#pragma unroll
            for (int nn = 0; nn < 4; ++nn) {
                float rk = r[nn][k];
                acc[nn].x += wv.x * rk;
                acc[nn].y += wv.y * rk;
                acc[nn].z += wv.z * rk;
                acc[nn].w += wv.w * rk;
            }
        }
    }
    // epilogue: prelu * dinv, project through M, shuffle-reduce across the 16 lanes
    float4 m0 = Ml[f4 * 4 + 0];
    float4 m1 = Ml[f4 * 4 + 1];
    float4 m2 = Ml[f4 * 4 + 2];
    float4 m3 = Ml[f4 * 4 + 3];
#pragma unroll
    for (int nn = 0; nn < 4; ++nn) {
        int v = v0 + nn;
        float dvm = (v < n) ? dinv[v] : 0.f;
        float ox = (fmaxf(acc[nn].x, 0.f) + s * fminf(acc[nn].x, 0.f)) * dvm;
        float oy = (fmaxf(acc[nn].y, 0.f) + s * fminf(acc[nn].y, 0.f)) * dvm;
        float oz = (fmaxf(acc[nn].z, 0.f) + s * fminf(acc[nn].z, 0.f)) * dvm;
        float ow = (fmaxf(acc[nn].w, 0.f) + s * fminf(acc[nn].w, 0.f)) * dvm;
        float px = ox * m0.x + oy * m1.x + oz * m2.x + ow * m3.x;
        float py = ox * m0.y + oy * m1.y + oz * m2.y + ow * m3.y;
        float pz = ox * m0.z + oy * m1.z + oz * m2.z + ow * m3.z;
        float pw = ox * m0.w + oy * m1.w + oz * m2.w + ow * m3.w;
#pragma unroll
        for (int mask = 8; mask >= 1; mask >>= 1) {
            px += __shfl_xor(px, mask, 16);
            py += __shfl_xor(py, mask, 16);
            pz += __shfl_xor(pz, mask, 16);
            pw += __shfl_xor(pw, mask, 16);
        }
        if (f4 == 0 && v < n) z[v] = make_float4(px, py, pz, pw);
    }
}

// ---------------- layer-4 aggregation + pooling in z-space (4-dim, L2-resident) --------
__global__ __launch_bounds__(256) void aggpool4_kernel(
    const float4* __restrict__ z, const int* __restrict__ row_off,
    const int* __restrict__ deg, const float* __restrict__ dinv,
    const int* __restrict__ csr_src, const int* __restrict__ batch,
    float* __restrict__ sums, float* __restrict__ cnt, int n) {
    __shared__ float lacc[NG * 4];
    __shared__ float lcnt[NG];
    int tid = threadIdx.x;
    if (tid < NG * 4) lacc[tid] = 0.f;
    if (tid < NG) lcnt[tid] = 0.f;
    __syncthreads();
    int v = blockIdx.x * 256 + tid;
    if (v < n) {
        float4 acc = z[v];
        int start = row_off[v], dcnt = deg[v];
        const int* __restrict__ row = csr_src + start;
        int j = 0;
        for (; j + 4 <= dcnt; j += 4) {
            float4 a0 = z[row[j]];
            float4 a1 = z[row[j + 1]];
            float4 a2 = z[row[j + 2]];
            float4 a3 = z[row[j + 3]];
            acc.x += (a0.x + a1.x) + (a2.x + a3.x);
            acc.y += (a0.y + a1.y) + (a2.y + a3.y);
            acc.z += (a0.z + a1.z) + (a2.z + a3.z);
            acc.w += (a0.w + a1.w) + (a2.w + a3.w);
        }
        for (; j < dcnt; ++j) {
            float4 a = z[row[j]];
            acc.x += a.x; acc.y += a.y; acc.z += a.z; acc.w += a.w;
        }
        float dv = dinv[v];
        int g = batch[v];
        float* lp = &lacc[g * 4];
        atomicAdd(lp + 0, acc.x * dv); atomicAdd(lp + 1, acc.y * dv);
        atomicAdd(lp + 2, acc.z * dv); atomicAdd(lp + 3, acc.w * dv);
        atomicAdd(&lcnt[g], 1.f);
    }
    __syncthreads();
    if (tid < NG * 4) {
        float val = lacc[tid];
        if (val != 0.f) atomicAdd(&sums[tid], val);
    }
    if (tid < NG) {
        float val = lcnt[tid];
        if (val != 0.f) atomicAdd(&cnt[tid], val);
    }
}

// ---------------- head: out[g][c] = sums[g][c]/cnt[g] + bb[c] ----------------
__global__ void head_kernel(const float* __restrict__ sums, const float* __restrict__ cnt,
                            const float* __restrict__ bb, float* __restrict__ out) {
    int t = threadIdx.x;          // 256 = 64 graphs * 4 classes
    int g = t >> 2, c = t & 3;
    out[t] = sums[t] / fmaxf(cnt[g], 1.f) + bb[c];
}

extern "C" void kernel_launch(void* const* d_in, const int* in_sizes, int n_in,
                              void* d_out, int out_size, void* d_ws, size_t ws_size,
                              hipStream_t stream) {
    const float* x    = (const float*)d_in[0];
    const int* esrc   = (const int*)d_in[1];
    const int* edst   = (const int*)d_in[2];
    const int* batch  = (const int*)d_in[3];
    const float* W1 = (const float*)d_in[4],  *b1 = (const float*)d_in[5];
    const float* W2 = (const float*)d_in[6],  *b2 = (const float*)d_in[7];
    const float* W3 = (const float*)d_in[8],  *b3 = (const float*)d_in[9];
    const float* W4 = (const float*)d_in[10], *b4 = (const float*)d_in[11];
    const float* a1 = (const float*)d_in[12];
    const float* a2 = (const float*)d_in[13];
    const float* a3 = (const float*)d_in[14];
    const float* Wlin = (const float*)d_in[15], *blin = (const float*)d_in[16];
    float* out = (float*)d_out;

    const int N = NN, E = NE;
    const int NB = (N + 1023) / 1024;                   // node-scan blocks (98)
    const int NBIN = (E + BIN_CHUNK - 1) / BIN_CHUNK;   // 196

    // workspace carve-up
    char* w = (char*)d_ws;
    size_t off = 0;
    auto alloc = [&](size_t bytes) { size_t r = off; off += (bytes + 255) & ~(size_t)255; return r; };
    size_t o_bcnt = alloc((size_t)NBUCK * 4);      // needs zero
    size_t o_pool = alloc((size_t)NG * 4 * 4);     // needs zero (pooled z sums)
    size_t o_cnt  = alloc((size_t)NG * 4);         // needs zero
    size_t zero_bytes = off;
    size_t o_deg  = alloc((size_t)N * 4);
    size_t o_dinv = alloc((size_t)N * 4);
    size_t o_roff = alloc((size_t)N * 4);
    size_t o_boff = alloc((size_t)NBUCK * 4);
    size_t o_bcur = alloc((size_t)NBUCK * 4);
    size_t o_bsum = alloc((size_t)128 * 4);
    size_t o_csrc = alloc((size_t)E * 4);
    size_t o_bin  = alloc((size_t)E * 4);          // packed (src<<7)|dst_low
    size_t o_X    = alloc((size_t)N * 8 * 4);      // prescaled x (fp32)
    size_t o_A    = alloc((size_t)N * 32 * 2);     // activations fp16 (max 32 halfs)
    size_t o_T    = alloc((size_t)N * 32 * 2);     // agg output fp16 (max 32 halfs)
    size_t o_z    = alloc((size_t)N * 4 * 4);      // z projections (float4/node)
    size_t o_M    = alloc((size_t)64 * 4 * 4);     // W4@Wlin
    size_t o_bb   = alloc((size_t)4 * 4);          // b4@Wlin + blin
    (void)ws_size;
    int*      bcnt   = (int*)(w + o_bcnt);
    float*    pool   = (float*)(w + o_pool);
    float*    cnt    = (float*)(w + o_cnt);
    int*      deg    = (int*)(w + o_deg);
    float*    dinv   = (float*)(w + o_dinv);
    int*      roff   = (int*)(w + o_roff);
    int*      boff   = (int*)(w + o_boff);
    int*      bcur   = (int*)(w + o_bcur);
    int*      bsum   = (int*)(w + o_bsum);
    int*      csrc   = (int*)(w + o_csrc);
    unsigned* binned = (unsigned*)(w + o_bin);
    float*    XS     = (float*)(w + o_X);
    char*     A      = (char*)(w + o_A);
    char*     T      = (char*)(w + o_T);
    float4*   z      = (float4*)(w + o_z);
    float*    M      = (float*)(w + o_M);
    float*    bb     = (float*)(w + o_bb);

    hipMemsetAsync(w, 0, zero_bytes, stream);

    // ---- head constants (independent; launch early) ----
    makeM_kernel<<<1, 256, 0, stream>>>(W4, b4, Wlin, blin, M, bb);

    // ---- CSR build via dst-bucket binning (once, reused by all 4 layers) ----
    bucket_hist_kernel<<<256, 256, 0, stream>>>(edst, bcnt, E);
    bucket_scan_kernel<<<1, 1024, 0, stream>>>(bcnt, boff, bcur);
    bin_kernel<<<NBIN, 256, 0, stream>>>(esrc, edst, bcur, binned, E);
    deg_dinv_kernel<<<NBUCK, 256, 0, stream>>>(binned, boff, bcnt, deg, dinv, N);
    scan1_kernel<<<NB, 1024, 0, stream>>>(deg, roff, bsum, N);
    scan2_kernel<<<1, 128, 0, stream>>>(bsum, NB);
    scan3_kernel<<<(N + 255) / 256, 256, 0, stream>>>(roff, bsum, N);
    build2_kernel<<<NBUCK, 256, 0, stream>>>(binned, boff, bcnt, roff, csrc, N);

    // ---- layer 1: agg(dinv*x)[8] @ W1 -> 16, prelu a1, output pre-scaled (fp16) ----
    prescale_kernel<<<(N * 2 + 255) / 256, 256, 0, stream>>>(x, dinv, XS, N);
    agg8_kernel<<<(N * 2 + 255) / 256, 256, 0, stream>>>(XS, roff, deg, dinv, csrc, (float2*)T, N);
    matmul_kernel<8, 16, true><<<(N + 255) / 256, 256, 0, stream>>>(
        (const float4*)T, W1, b1, a1, dinv, (float2*)A, N);

    // ---- layer 2 ----
    agg_h_kernel<16><<<(N * 2 + 255) / 256, 256, 0, stream>>>(
        (const float4*)A, roff, deg, dinv, csrc, (float4*)T, N);
    matmul_kernel<16, 32, true><<<(N + 127) / 128, 256, 0, stream>>>(
        (const float4*)T, W2, b2, a2, dinv, (float2*)A, N);

    // ---- layer 3: agg -> matmul_z (z = dinv*prelu(row) @ M; A never materialized) ----
    agg_h_kernel<32><<<(N * 4 + 255) / 256, 256, 0, stream>>>(
        (const float4*)A, roff, deg, dinv, csrc, (float4*)T, N);
    matmul_z_kernel<<<(N + 63) / 64, 256, 0, stream>>>(
        (const float4*)T, W3, b3, a3, dinv, M, z, N);

    // ---- layer 4 in z-space: gather-aggregate + pool over N x 4 (L2-resident) ----
    aggpool4_kernel<<<(N + 255) / 256, 256, 0, stream>>>(
        z, roff, deg, dinv, csrc, batch, pool, cnt, N);
    head_kernel<<<1, 256, 0, stream>>>(pool, cnt, bb, out);
}